// Round 4
// baseline (702.530 us; speedup 1.0000x reference)
//
#include <hip/hip_runtime.h>
#include <cstdint>

// ---------------------------------------------------------------------------
// NVFP4 fake-quant GEMM: out = fq4(x) @ fq4(w)^T + bias
// fq4: per-16-group (along K) scale = e4m3_rt(amax/6), values on e2m1 grid.
// dq = q*scale is EXACT in bf16 -> quantize to bf16 in d_ws, bf16-MFMA GEMM.
//
// GEMM v4 (m201-faithful): 256x256, BK=64, 8 waves, 16x16x32 MFMA.
// Key vs v2: ds_reads issued ONE PHASE AHEAD of their MFMA use
// ({4,8,8,4} reads/phase, never 12), counted lgkmcnt(n_phase) at phase end
// (runtime no-op; forces prev phase's reads serviced -> WAR-safe staging),
// uniform counted vmcnt(10) (waits only loads issued a full tile earlier),
// 2 barriers/phase lockstep, setprio around MFMA, static 2-tile unroll.
// ---------------------------------------------------------------------------

typedef __attribute__((ext_vector_type(8))) __bf16 bf16x8;
typedef __attribute__((ext_vector_type(4))) float f32x4;

typedef __attribute__((address_space(1))) void gvoid;
typedef __attribute__((address_space(3))) void lvoid;

__device__ __forceinline__ float fp8_e4m3_rt(float x) {
    if (x < 0.015625f) {
        return __builtin_rintf(x * 512.0f) * (1.0f / 512.0f);
    }
    unsigned u = __float_as_uint(x);
    unsigned lsb = (u >> 20) & 1u;
    u = (u + 0x7FFFFu + lsb) & ~0xFFFFFu;
    return __uint_as_float(u);
}

// Divide-free e2m1 bucket of fl32(|v|/scale) (proved exact; passed absmax=0).
__device__ __forceinline__ uint2 quant_quad(float4 v) {
    float ax = fabsf(v.x), ay = fabsf(v.y), az = fabsf(v.z), aw = fabsf(v.w);
    float a = fmaxf(fmaxf(ax, ay), fmaxf(az, aw));
    a = fmaxf(a, __shfl_xor(a, 1));
    a = fmaxf(a, __shfl_xor(a, 2));
    float scale = fp8_e4m3_rt(a / 6.0f);
    float sN = -scale;
    float n0 = sN * 0x1p-27f;
    float n1 = sN * 0x1p-25f;
    float n2 = sN * 0x1p-24f;
    float n4 = sN * 0x1p-23f;
    float n6 = sN * 0x1p-22f;
    float e[4] = {v.x, v.y, v.z, v.w};
    unsigned r[4];
    #pragma unroll
    for (int i = 0; i < 4; ++i) {
        float av = fabsf(e[i]);
        float q =
            fmaf(sN, 0.25f, av) < n0 ? 0.0f :
            fmaf(sN, 0.75f, av) < n1 ? 0.5f :
            fmaf(sN, 1.25f, av) < n2 ? 1.0f :
            fmaf(sN, 1.75f, av) < n2 ? 1.5f :
            fmaf(sN, 2.5f,  av) < n4 ? 2.0f :
            fmaf(sN, 3.5f,  av) < n4 ? 3.0f :
            fmaf(sN, 5.0f,  av) < n6 ? 4.0f : 6.0f;
        float dq = q * scale;
        r[i] = (__float_as_uint(dq) | (__float_as_uint(e[i]) & 0x80000000u)) >> 16;
    }
    uint2 o;
    o.x = r[0] | (r[1] << 16);
    o.y = r[2] | (r[3] << 16);
    return o;
}

__global__ __launch_bounds__(256)
void quant_fp4_fused(const float* __restrict__ x, const float* __restrict__ w,
                     uint16_t* __restrict__ out, int xquads, int totquads) {
    const int half = totquads >> 1;
    const int t0 = blockIdx.x * 256 + threadIdx.x;
    uint2* o2 = (uint2*)out;
    if (t0 < half) {
        const float4* s0 = (t0 < xquads) ? ((const float4*)x) + t0
                                         : ((const float4*)w) + (t0 - xquads);
        o2[t0] = quant_quad(*s0);
    }
    const int q1 = t0 + half;
    if (q1 < totquads) {
        const float4* s1 = (q1 < xquads) ? ((const float4*)x) + q1
                                         : ((const float4*)w) + (q1 - xquads);
        o2[q1] = quant_quad(*s1);
    }
}

// ---------------------------------------------------------------------------
// GEMM. LDS: lds[2][2][256*64] bf16 = 128 KiB.
// A region: physical row = logical row (0..255).  A-half mh -> chunks {mh,mh+2}.
// B region: physical row p = wn*32 + fj*16 + l15 + nh*128 (nh-halves chunk-
//   aligned: nh0 = chunks {0,1}, nh1 = {2,3}).
// Swizzle: (row,k) stored at elem row*64 + (k ^ ((row&7)<<3)); staging writes
//   linear chunks from inverse-permuted global source.
// Schedule per tile t (buf B=t&1), quadrants (0,0),(0,1),(1,1),(1,0):
//   ph0: rd B1(t)[4]      stage A{0,2}(t+2)  lgkm(4) vm(10) bar MFMA(0,0) bar
//   ph1: rd A1(t)[8]      stage B{0,1}(t+2)  lgkm(8) vm(10) bar MFMA(0,1) bar
//   ph2: rd A0(t+1)[8]    stage B{2,3}(t+2)  lgkm(8) vm(10) bar MFMA(1,1) bar
//   ph3: rd B0(t+1)[4]    stage A{1,3}(t+2)  lgkm(4) vm(10) bar MFMA(1,0) bar
// Ledger: every region staged exactly 2 phases after its last LDS-read
// (service forced by the counted lgkm one phase after issue + barrier).
// vmcnt(10) always targets the 2 loads issued 4 phases (1 tile) earlier.
// ---------------------------------------------------------------------------
#define BK 64
#define THREADS 512

#define SB __builtin_amdgcn_sched_barrier(0)

#define LDA(dst, B_, mh) do { _Pragma("unroll")                               \
    for (int fi_ = 0; fi_ < 4; ++fi_) {                                       \
        dst[fi_][0] = *(const bf16x8*)&lds[B_][0][aRowA + (mh)*4096 + fi_*1024 + kx0]; \
        dst[fi_][1] = *(const bf16x8*)&lds[B_][0][aRowA + (mh)*4096 + fi_*1024 + kx1]; \
    } } while (0)

#define LDB(dst, B_, nh) do { _Pragma("unroll")                               \
    for (int fj_ = 0; fj_ < 2; ++fj_) {                                       \
        dst[fj_][0] = *(const bf16x8*)&lds[B_][1][bRowB + (nh)*8192 + fj_*1024 + kx0]; \
        dst[fj_][1] = *(const bf16x8*)&lds[B_][1][bRowB + (nh)*8192 + fj_*1024 + kx1]; \
    } } while (0)

#define STGA(B_, ch, ko) __builtin_amdgcn_global_load_lds(                    \
    (gvoid*)(pA + offA[ch] + kAdv + (ko)),                                    \
    (lvoid*)&lds[B_][0][(ch)*4096 + ldsU], 16, 0, 0)
#define STGB(B_, ch, ko) __builtin_amdgcn_global_load_lds(                    \
    (gvoid*)(pB + offB[ch] + kAdv + (ko)),                                    \
    (lvoid*)&lds[B_][1][(ch)*4096 + ldsU], 16, 0, 0)

#define QUAD(A_, Bf_, mh, nh) do {                                            \
    __builtin_amdgcn_s_setprio(1);                                            \
    _Pragma("unroll") for (int fi_ = 0; fi_ < 4; ++fi_)                       \
    _Pragma("unroll") for (int fj_ = 0; fj_ < 2; ++fj_) {                     \
        f32x4 c_ = acc[(mh)*4 + fi_][(nh)*2 + fj_];                           \
        c_ = __builtin_amdgcn_mfma_f32_16x16x32_bf16(A_[fi_][0], Bf_[fj_][0], c_, 0, 0, 0); \
        c_ = __builtin_amdgcn_mfma_f32_16x16x32_bf16(A_[fi_][1], Bf_[fj_][1], c_, 0, 0, 0); \
        acc[(mh)*4 + fi_][(nh)*2 + fj_] = c_;                                 \
    }                                                                         \
    __builtin_amdgcn_s_setprio(0); } while (0)

#define PHEND do { SB; __builtin_amdgcn_s_barrier(); SB; } while (0)

#define KTILE(B_, STG_, AHD_, SK_) do {                                       \
    /* ph0 */                                                                 \
    LDB(b1, B_, 1);                                                           \
    if (STG_) { STGA(B_, 0, SK_); STGA(B_, 2, SK_); }                         \
    asm volatile("s_waitcnt lgkmcnt(4)" ::: "memory");                        \
    if (STG_) { asm volatile("s_waitcnt vmcnt(10)" ::: "memory"); }           \
    else      { asm volatile("s_waitcnt vmcnt(0)"  ::: "memory"); }           \
    SB; __builtin_amdgcn_s_barrier(); SB;                                     \
    QUAD(a0, b0, 0, 0);                                                       \
    PHEND;                                                                    \
    /* ph1 */                                                                 \
    LDA(a1, B_, 1);                                                           \
    if (STG_) { STGB(B_, 0, SK_); STGB(B_, 1, SK_); }                         \
    asm volatile("s_waitcnt lgkmcnt(8)" ::: "memory");                        \
    if (STG_) { asm volatile("s_waitcnt vmcnt(10)" ::: "memory"); }           \
    SB; __builtin_amdgcn_s_barrier(); SB;                                     \
    QUAD(a0, b1, 0, 1);                                                       \
    PHEND;                                                                    \
    /* ph2 */                                                                 \
    if (AHD_) { LDA(a0, (B_) ^ 1, 0); }                                       \
    if (STG_) { STGB(B_, 2, SK_); STGB(B_, 3, SK_); }                         \
    if (AHD_) { asm volatile("s_waitcnt lgkmcnt(8)" ::: "memory"); }          \
    else      { asm volatile("s_waitcnt lgkmcnt(0)" ::: "memory"); }          \
    if (STG_) { asm volatile("s_waitcnt vmcnt(10)" ::: "memory"); }           \
    SB; __builtin_amdgcn_s_barrier(); SB;                                     \
    QUAD(a1, b1, 1, 1);                                                       \
    PHEND;                                                                    \
    /* ph3 */                                                                 \
    if (AHD_) { LDB(nb0, (B_) ^ 1, 0); }                                      \
    if (STG_) { STGA(B_, 1, SK_); STGA(B_, 3, SK_); }                         \
    if (AHD_) { asm volatile("s_waitcnt lgkmcnt(4)" ::: "memory"); }          \
    else      { asm volatile("s_waitcnt lgkmcnt(0)" ::: "memory"); }          \
    if (STG_) { asm volatile("s_waitcnt vmcnt(10)" ::: "memory"); }           \
    SB; __builtin_amdgcn_s_barrier(); SB;                                     \
    QUAD(a1, b0, 1, 0);                                                       \
    if (AHD_) { _Pragma("unroll") for (int z_ = 0; z_ < 2; ++z_) {            \
        b0[z_][0] = nb0[z_][0]; b0[z_][1] = nb0[z_][1]; } }                   \
    PHEND;                                                                    \
    } while (0)

__global__ __launch_bounds__(THREADS, 2)
void gemm_w4a4(const uint16_t* __restrict__ Aq, const uint16_t* __restrict__ Bq,
               const float* __restrict__ bias, float* __restrict__ C,
               int M, int N, int K) {
    __shared__ __align__(16) uint16_t lds[2][2][256 * BK];

    const int tid  = threadIdx.x;
    const int wave = tid >> 6;
    const int lane = tid & 63;
    const int wm   = wave >> 2;            // 0..1  (m half)
    const int wn   = wave & 3;             // 0..3  (n quarter)
    const int l15  = lane & 15;
    const int hi16 = (lane >> 4) << 3;     // 0/8/16/24 (frag k subgroup)
    const int rsw  = (lane & 7) << 3;      // row-swizzle XOR (elems)
    const int kx0  = hi16 ^ rsw;           // k-step 0
    const int kx1  = (32 + hi16) ^ rsw;    // k-step 1
    const int aRowA = ((wm << 7) + l15) << 6;
    const int bRowB = ((wn << 5) + l15) << 6;
    const int ldsU  = wave << 9;

    // ---- bijective XCD swizzle (T1, m204) ----
    const int ntm = M >> 8, nwg = ntm * (N >> 8);
    const int bid = blockIdx.x;
    const int q8 = nwg >> 3, r8 = nwg & 7;
    const int xcd = bid & 7;
    const int wgid = (xcd < r8 ? xcd * (q8 + 1) : r8 * (q8 + 1) + (xcd - r8) * q8)
                     + (bid >> 3);
    const int mBase = (wgid % ntm) << 8;
    const int nBase = (wgid / ntm) << 8;

    // ---- staging source offsets (inverse-swizzled; B row-remapped) ----
    uint32_t offA[4], offB[4];
    #pragma unroll
    for (int i = 0; i < 4; ++i) {
        const int c = i * THREADS + tid;
        const int p = c >> 3;                       // physical row
        const int kc = ((c & 7) ^ (p & 7)) << 3;    // inverse swizzle
        offA[i] = (uint32_t)p * (uint32_t)K + (uint32_t)kc;
        const int nh = p >> 7, wnn = (p >> 5) & 3, r = p & 31;
        const int Lr = wnn * 64 + nh * 32 + r;      // logical B row
        offB[i] = (uint32_t)Lr * (uint32_t)K + (uint32_t)kc;
    }
    const uint16_t* pA = Aq + (size_t)mBase * K;
    const uint16_t* pB = Bq + (size_t)nBase * K;

    const int nt = K / BK;   // assumed even, >= 4 (K=4096 -> 64)

    // k-origin advance for staging; during iteration tk it points at the
    // k-base such that kAdv + SK_ is tile tk+2's k (SK_ in {0, BK}).
    uint32_t kAdv = 0;

    // ---- prologue: stage t0, t1 in the canonical per-tile order ----
    STGA(0, 0, 0); STGA(0, 2, 0); STGB(0, 0, 0); STGB(0, 1, 0);
    STGB(0, 2, 0); STGB(0, 3, 0); STGA(0, 1, 0); STGA(0, 3, 0);
    STGA(1, 0, 64); STGA(1, 2, 64); STGB(1, 0, 64); STGB(1, 1, 64);
    STGB(1, 2, 64); STGB(1, 3, 64); STGA(1, 1, 64); STGA(1, 3, 64);
    asm volatile("s_waitcnt vmcnt(8)" ::: "memory");   // t0 landed
    SB; __builtin_amdgcn_s_barrier(); SB;

    f32x4 acc[8][4] = {};
    bf16x8 a0[4][2], a1[4][2], b0[2][2], b1[2][2], nb0[2][2];

    // prologue ahead-reads for tile 0's ph0 quadrant
    LDA(a0, 0, 0);
    LDB(b0, 0, 0);

    kAdv = 2 * BK;    // during iteration tk: tile tk+2's k-origin (SK_=0 path)

    for (int tk = 0; tk < nt - 2; tk += 2) {
        KTILE(0, 1, 1, 0);
        KTILE(1, 1, 1, 64);
        kAdv += 2 * BK;
    }
    // tail: tiles nt-2 (buf0, no stage) and nt-1 (buf1, no stage/ahead)
    KTILE(0, 0, 1, 0);
    KTILE(1, 0, 0, 0);

    // ---- epilogue: C/D col = lane&15, row = (lane>>4)*4 + reg ----
    const int rq = (lane >> 4) << 2;
    #pragma unroll
    for (int j = 0; j < 4; ++j) {
        const int col = nBase + (wn << 6) + j * 16 + l15;
        const float bj = bias[col];
        #pragma unroll
        for (int i = 0; i < 8; ++i) {
            const int row0 = mBase + (wm << 7) + i * 16 + rq;
            #pragma unroll
            for (int r = 0; r < 4; ++r)
                C[(size_t)(row0 + r) * N + col] = acc[i][j][r] + bj;
        }
    }
}

extern "C" void kernel_launch(void* const* d_in, const int* in_sizes, int n_in,
                              void* d_out, int out_size, void* d_ws, size_t ws_size,
                              hipStream_t stream) {
    const float* x    = (const float*)d_in[0];
    const float* w    = (const float*)d_in[1];
    const float* bias = (const float*)d_in[2];
    float* out = (float*)d_out;

    const int N = in_sizes[2];
    const int K = in_sizes[1] / N;
    const int M = in_sizes[0] / K;

    uint16_t* xq = (uint16_t*)d_ws;
    uint16_t* wq = xq + (size_t)M * K;

    const int xquads = (M * K) / 4;
    const int totquads = xquads + (N * K) / 4;
    const int half = totquads / 2;
    quant_fp4_fused<<<(half + 255) / 256, 256, 0, stream>>>(x, w, xq, xquads, totquads);

    const int nwg = (M >> 8) * (N >> 8);
    gemm_w4a4<<<nwg, THREADS, 0, stream>>>(xq, wq, bias, out, M, N, K);
}